// Round 1
// baseline (12996.742 us; speedup 1.0000x reference)
//
#include <hip/hip_runtime.h>
#include <hip/hip_fp16.h>
#include <stdint.h>

typedef _Float16 f16;
typedef _Float16 v8h __attribute__((ext_vector_type(8)));
typedef float v4f __attribute__((ext_vector_type(4)));

#define AS1 __attribute__((address_space(1)))
#define AS3 __attribute__((address_space(3)))

// async global->LDS, 16B per lane, dest = wave-uniform base + lane*16
__device__ __forceinline__ void gld_lds16(const f16* g, f16* l) {
  __builtin_amdgcn_global_load_lds((AS1 void*)g, (AS3 void*)l, 16, 0, 0);
}

__device__ __forceinline__ float fsig(float x) { return 1.f / (1.f + __expf(-x)); }
__device__ __forceinline__ float ftanh(float x) {
  float e = __expf(2.f * x);
  return 1.f - 2.f / (e + 1.f);
}

__device__ __forceinline__ float dot8(const f16* wp, v8h s8) {
  v8h w8 = *(const v8h*)wp;
  float r = 0.f;
#pragma unroll
  for (int j = 0; j < 8; ++j) r += (float)w8[j] * (float)s8[j];
  return r;
}

__device__ __forceinline__ void st4h(f16* d, float4 f) {
  union { f16 h[4]; uint2 u; } o;
  o.h[0] = (f16)f.x; o.h[1] = (f16)f.y; o.h[2] = (f16)f.z; o.h[3] = (f16)f.w;
  *(uint2*)d = o.u;
}

// ---------------- prep: fp32->fp16 conversions / gathers / reorders ----------
// group = 4 consecutive elements
#define C_WPAIR 12288000ULL
#define C_AHJ   (C_WPAIR + 1048576ULL)
#define C_AE    (C_AHJ + 131072ULL)
#define C_WAH   (C_AE + 32768ULL)
#define C_WAS   (C_WAH + 16384ULL)
#define C_WHH   (C_WAS + 49152ULL)
#define C_WCT   (C_WHH + 98304ULL)
#define C_WET   (C_WCT + 24576ULL)
#define C_BIASP (C_WET + 16000ULL)

__global__ __launch_bounds__(256) void prep(
    const float* __restrict__ Wmo, const float* __restrict__ hj,
    const int* __restrict__ y, const float* __restrict__ emb,
    const float* __restrict__ Wa, const float* __restrict__ Wih,
    const float* __restrict__ Whhf, const float* __restrict__ bmo,
    f16* __restrict__ Wpair, f16* __restrict__ Ahj, f16* __restrict__ Ae,
    f16* __restrict__ Wah, f16* __restrict__ Was, f16* __restrict__ Whh,
    f16* __restrict__ Wct, f16* __restrict__ Wet, float* __restrict__ biasp)
{
  for (size_t g = (size_t)blockIdx.x * blockDim.x + threadIdx.x; g < C_BIASP;
       g += (size_t)gridDim.x * blockDim.x) {
    if (g < C_WPAIR) {                       // W_pair[2v+j] = W_mo[j*32000+v]
      size_t row = g / 192, kk = (g % 192) * 4;
      size_t jj = row & 1, v = row >> 1;
      float4 f = *(const float4*)(Wmo + (jj * 32000 + v) * 768 + kk);
      st4h(Wpair + row * 768 + kk, f);
    } else if (g < C_AHJ) {                  // h_j flat -> f16 (8192x512)
      size_t i = (g - C_WPAIR) * 4;
      float4 f = *(const float4*)(hj + i);
      st4h(Ahj + i, f);
    } else if (g < C_AE) {                   // emb gather, rows m = t*64+b
      size_t i = g - C_AHJ;
      size_t m = i >> 5, kk = (i & 31) * 4;
      int yy = y[(m & 63) * 64 + (m >> 6)];
      float4 f = make_float4(0.f, 0.f, 0.f, 0.f);
      if (yy != 0) f = *(const float4*)(emb + (size_t)yy * 128 + kk);
      st4h(Ae + m * 128 + kk, f);
    } else if (g < C_WAH) {                  // W_a[:,256:768] rows (256x512)
      size_t i = g - C_AE;
      size_t n = i >> 7, kk = (i & 127) * 4;
      float4 f = *(const float4*)(Wa + n * 768 + 256 + kk);
      st4h(Wah + n * 512 + kk, f);
    } else if (g < C_WAS) {                  // W_a[:,0:256] rows (256x256)
      size_t i = g - C_WAH;
      size_t n = i >> 6, kk = (i & 63) * 4;
      float4 f = *(const float4*)(Wa + n * 768 + kk);
      st4h(Was + n * 256 + kk, f);
    } else if (g < C_WHH) {                  // W_hh copy (768x256)
      size_t i = (g - C_WAS) * 4;
      float4 f = *(const float4*)(Whhf + i);
      st4h(Whh + i, f);
    } else if (g < C_WCT) {                  // W_ih[:,128:640] rows (768x512)
      size_t i = g - C_WHH;
      size_t n = i >> 7, kk = (i & 127) * 4;
      float4 f = *(const float4*)(Wih + n * 640 + 128 + kk);
      st4h(Wct + n * 512 + kk, f);
    } else if (g < C_WET) {                  // W_ih[:,0:128] rows (768x128)
      size_t i = g - C_WCT;
      size_t n = i >> 5, kk = (i & 31) * 4;
      float4 f = *(const float4*)(Wih + n * 640 + kk);
      st4h(Wet + n * 128 + kk, f);
    } else {                                 // bias_pair[n] = b_mo[(n&1)*V + n/2]
      size_t i = g - C_WET;
      size_t n = i * 4;
#pragma unroll
      for (int u = 0; u < 4; ++u) {
        size_t nn = n + u;
        biasp[nn] = bmo[(nn & 1) * 32000 + (nn >> 1)];
      }
    }
  }
}

// ---------------- generic 128x128x(BK=32) fp16 MFMA GEMM, C = A * Bt^T -------
// A: MxK row-major f16; Bt: NxK row-major f16 (i.e. B transposed)
// MODE 0: store f16 C[m*N+n]
// MODE 1: store f16 C[m*N+n] + bias[n]
// MODE 2: store f16 transposed-per-batch: C[((m>>7)*N + n)*128 + (m&127)]
// MODE 3: final: v = acc + bias[n]; out[m*32000 + n/2] = max over pair (shfl^1)
template <int MODE>
__global__ __launch_bounds__(256) void gemm_k(
    const f16* __restrict__ A, const f16* __restrict__ Bt,
    void* __restrict__ Cout, const float* __restrict__ bias,
    int K, int N, int gridMtiles)
{
  __shared__ __align__(16) f16 As[128 * 32];
  __shared__ __align__(16) f16 Bs[128 * 32];
  const int bid = blockIdx.x;
  const int mt = bid % gridMtiles, nt = bid / gridMtiles;
  const int m0 = mt << 7, n0 = nt << 7;
  const int tid = threadIdx.x;
  const int wave = tid >> 6, lane = tid & 63;
  const int sr = lane >> 2;              // staging row-in-16
  const int sc8 = (lane & 3) << 3;       // staging col (halves)
  const int q = lane >> 4, rm = lane & 15;
  const int wm = (wave & 1) << 6, wn = (wave >> 1) << 6;

  v4f acc[4][4];
#pragma unroll
  for (int i = 0; i < 4; ++i)
#pragma unroll
    for (int j = 0; j < 4; ++j) acc[i][j] = (v4f){0.f, 0.f, 0.f, 0.f};

  const f16* Abase = A + (size_t)m0 * K;
  const f16* Bbase = Bt + (size_t)n0 * K;

  for (int k0 = 0; k0 < K; k0 += 32) {
#pragma unroll
    for (int p = 0; p < 2; ++p) {
      const int c = wave * 2 + p;
      const int r = c * 16 + sr;
      gld_lds16(Abase + (size_t)r * K + k0 + sc8, As + c * 512);
      gld_lds16(Bbase + (size_t)r * K + k0 + sc8, Bs + c * 512);
    }
    __syncthreads();
    v8h af[4], bf[4];
#pragma unroll
    for (int i = 0; i < 4; ++i) {
      af[i] = *(const v8h*)(As + (wm + i * 16 + rm) * 32 + q * 8);
      bf[i] = *(const v8h*)(Bs + (wn + i * 16 + rm) * 32 + q * 8);
    }
#pragma unroll
    for (int mi = 0; mi < 4; ++mi)
#pragma unroll
      for (int ni = 0; ni < 4; ++ni)
        acc[mi][ni] = __builtin_amdgcn_mfma_f32_16x16x32_f16(
            af[mi], bf[ni], acc[mi][ni], 0, 0, 0);
    __syncthreads();
  }

#pragma unroll
  for (int mi = 0; mi < 4; ++mi)
#pragma unroll
    for (int ni = 0; ni < 4; ++ni)
#pragma unroll
      for (int reg = 0; reg < 4; ++reg) {
        const int gm = m0 + wm + mi * 16 + q * 4 + reg;
        const int gn = n0 + wn + ni * 16 + rm;
        float v = acc[mi][ni][reg];
        if constexpr (MODE == 0) {
          ((f16*)Cout)[(size_t)gm * N + gn] = (f16)v;
        } else if constexpr (MODE == 1) {
          v += bias[gn];
          ((f16*)Cout)[(size_t)gm * N + gn] = (f16)v;
        } else if constexpr (MODE == 2) {
          ((f16*)Cout)[((size_t)(gm >> 7) * N + gn) * 128 + (gm & 127)] = (f16)v;
        } else {
          v += bias[gn];
          float o = __shfl_xor(v, 1);
          v = fmaxf(v, o);
          if (!(lane & 1))
            ((float*)Cout)[(size_t)gm * 32000 + (gn >> 1)] = v;
        }
      }
}

// ---------------- recurrence: 1 block per batch, 64 steps, no grid sync ------
__global__ __launch_bounds__(512) void recur_k(
    const f16* __restrict__ Whh, const f16* __restrict__ Was,
    const f16* __restrict__ hjWcT, const f16* __restrict__ hjp,
    const f16* __restrict__ hjf, const f16* __restrict__ gie,
    const float* __restrict__ bhh, const float* __restrict__ va,
    f16* __restrict__ sc)
{
  const int b = blockIdx.x, tid = threadIdx.x;
  const int wv = tid >> 6, lane = tid & 63;
  const int ks = lane >> 4, hl = lane & 15;
  __shared__ __align__(16) f16 s_buf[2][256];
  __shared__ __align__(16) f16 alpha[128];
  __shared__ __align__(16) f16 sp[256];
  __shared__ __align__(16) f16 va_l[256];
  __shared__ float energy[128];
  __shared__ float bhh_l[768];

  for (int i = tid; i < 768; i += 512) bhh_l[i] = bhh[i];
  if (tid < 256) { va_l[tid] = (f16)va[tid]; s_buf[0][tid] = (f16)0.f; }
  if (tid < 128) alpha[tid] = (f16)0.f;
  __syncthreads();

  const f16* hjWb = hjWcT + (size_t)b * 98304;  // 768*128
  const f16* hjpb = hjp + (size_t)b * 32768;    // 128*256
  const f16* hjfb = hjf + (size_t)b * 65536;    // 128*512

  for (int t = 0; t < 64; ++t) {
    const int cur = t & 1, nxt = cur ^ 1;
    const size_t srow = ((size_t)b * 64 + t) * 768;
    const f16* grow = gie + ((size_t)t * 64 + b) * 768;

    // preload k-slices of s (K=256) and alpha (K=128) for this lane's ks
    v8h sA[8], aA[4];
#pragma unroll
    for (int i = 0; i < 8; ++i) sA[i] = *(const v8h*)(&s_buf[cur][ks * 64 + i * 8]);
#pragma unroll
    for (int i = 0; i < 4; ++i) aA[i] = *(const v8h*)(&alpha[ks * 32 + i * 8]);

    // ---- phase A: gh (s.Whh) + gi_c (alpha.hjWc) -> gates -> s_new
#pragma unroll
    for (int hg = 0; hg < 2; ++hg) {
      const int h = wv * 32 + hg * 16 + hl;
      float d_r = 0.f, d_z = 0.f, g_n = 0.f, e_n = 0.f;
      const f16* wr = Whh + (size_t)h * 256 + ks * 64;
      const f16* wz = Whh + (size_t)(256 + h) * 256 + ks * 64;
      const f16* wn_ = Whh + (size_t)(512 + h) * 256 + ks * 64;
      const f16* cr = hjWb + (size_t)h * 128 + ks * 32;
      const f16* cz = hjWb + (size_t)(256 + h) * 128 + ks * 32;
      const f16* cn = hjWb + (size_t)(512 + h) * 128 + ks * 32;
#pragma unroll
      for (int i = 0; i < 8; ++i) {
        d_r += dot8(wr + i * 8, sA[i]);
        d_z += dot8(wz + i * 8, sA[i]);
        g_n += dot8(wn_ + i * 8, sA[i]);
      }
#pragma unroll
      for (int i = 0; i < 4; ++i) {
        d_r += dot8(cr + i * 8, aA[i]);
        d_z += dot8(cz + i * 8, aA[i]);
        e_n += dot8(cn + i * 8, aA[i]);
      }
      d_r += __shfl_xor(d_r, 16); d_r += __shfl_xor(d_r, 32);
      d_z += __shfl_xor(d_z, 16); d_z += __shfl_xor(d_z, 32);
      g_n += __shfl_xor(g_n, 16); g_n += __shfl_xor(g_n, 32);
      e_n += __shfl_xor(e_n, 16); e_n += __shfl_xor(e_n, 32);
      if (ks == 0) {
        float rr = fsig(bhh_l[h] + (float)grow[h] + d_r);
        float zz = fsig(bhh_l[256 + h] + (float)grow[256 + h] + d_z);
        float nn = ftanh((float)grow[512 + h] + e_n + rr * (bhh_l[512 + h] + g_n));
        float sn = (1.f - zz) * nn + zz * (float)s_buf[cur][h];
        s_buf[nxt][h] = (f16)sn;
        sc[srow + h] = (f16)sn;
      }
    }
    __syncthreads();

    // ---- phase B: s_proj = s_new . W_a_s rows
    {
      v8h sN[8];
#pragma unroll
      for (int i = 0; i < 8; ++i) sN[i] = *(const v8h*)(&s_buf[nxt][ks * 64 + i * 8]);
#pragma unroll
      for (int hg = 0; hg < 2; ++hg) {
        const int h = wv * 32 + hg * 16 + hl;
        const f16* wa = Was + (size_t)h * 256 + ks * 64;
        float a2 = 0.f;
#pragma unroll
        for (int i = 0; i < 8; ++i) a2 += dot8(wa + i * 8, sN[i]);
        a2 += __shfl_xor(a2, 16); a2 += __shfl_xor(a2, 32);
        if (ks == 0) sp[h] = (f16)a2;
      }
    }
    __syncthreads();

    // ---- phase C: energy[tx] = sum_h tanh(sp+hjp)*va
    {
      const int tx = wv * 16 + hl;
      const f16* hr = hjpb + (size_t)tx * 256 + ks * 64;
      float a3 = 0.f;
#pragma unroll
      for (int i = 0; i < 8; ++i) {
        v8h hj8 = *(const v8h*)(hr + i * 8);
        v8h sp8 = *(const v8h*)(&sp[ks * 64 + i * 8]);
        v8h va8 = *(const v8h*)(&va_l[ks * 64 + i * 8]);
#pragma unroll
        for (int j = 0; j < 8; ++j)
          a3 += ftanh((float)sp8[j] + (float)hj8[j]) * (float)va8[j];
      }
      a3 += __shfl_xor(a3, 16); a3 += __shfl_xor(a3, 32);
      if (ks == 0) energy[tx] = a3;
    }
    __syncthreads();

    // ---- softmax over tx (one wave)
    if (tid < 64) {
      float e0 = energy[tid], e1 = energy[tid + 64];
      float mx = fmaxf(e0, e1);
#pragma unroll
      for (int off = 32; off; off >>= 1) mx = fmaxf(mx, __shfl_xor(mx, off));
      float x0 = __expf(e0 - mx), x1 = __expf(e1 - mx);
      float ssum = x0 + x1;
#pragma unroll
      for (int off = 32; off; off >>= 1) ssum += __shfl_xor(ssum, off);
      float inv = 1.f / ssum;
      alpha[tid] = (f16)(x0 * inv);
      alpha[tid + 64] = (f16)(x1 * inv);
    }
    __syncthreads();

    // ---- phase F: c_new[k] = sum_tx alpha[tx]*h_j[tx][k]; store to sc
    {
      const f16* hp = hjfb + tid;
      float a4 = 0.f;
#pragma unroll 4
      for (int txb = 0; txb < 16; ++txb) {
        v8h a8 = *(const v8h*)(&alpha[txb * 8]);
#pragma unroll
        for (int j = 0; j < 8; ++j)
          a4 += (float)a8[j] * (float)hp[(size_t)(txb * 8 + j) * 512];
      }
      sc[srow + 256 + tid] = (f16)a4;
    }
    __syncthreads();
  }
}

// ---------------- launch ------------------------------------------------------
extern "C" void kernel_launch(void* const* d_in, const int* in_sizes, int n_in,
                              void* d_out, int out_size, void* d_ws, size_t ws_size,
                              hipStream_t stream)
{
  const int*   y    = (const int*)d_in[0];
  const float* hj   = (const float*)d_in[1];
  const float* emb  = (const float*)d_in[2];
  const float* Wih  = (const float*)d_in[3];
  const float* Whhf = (const float*)d_in[4];
  const float* bih  = (const float*)d_in[5];
  const float* bhh  = (const float*)d_in[6];
  const float* Wa   = (const float*)d_in[7];
  const float* va   = (const float*)d_in[8];
  const float* Wmo  = (const float*)d_in[9];
  const float* bmo  = (const float*)d_in[10];

  char* ws = (char*)d_ws;
  f16*   Wpair = (f16*)(ws);                   // 64000x768        98,304,000 B
  f16*   Ahj   = (f16*)(ws + 98304000);        // 8192x512          8,388,608
  f16*   Ae    = (f16*)(ws + 106692608);       // 4096x128          1,048,576
  f16*   Wah   = (f16*)(ws + 107741184);       // 256x512             262,144
  f16*   Wasp  = (f16*)(ws + 108003328);       // 256x256             131,072
  f16*   Whhp  = (f16*)(ws + 108134400);       // 768x256             393,216
  f16*   Wct   = (f16*)(ws + 108527616);       // 768x512             786,432
  f16*   Wet   = (f16*)(ws + 109314048);       // 768x128             196,608
  float* biasp = (float*)(ws + 109510656);     // 64000               256,000
  f16*   hjp   = (f16*)(ws + 109766656);       // 8192x256          4,194,304
  f16*   gie   = (f16*)(ws + 113960960);       // 4096x768          6,291,456
  f16*   hjWcT = (f16*)(ws + 120252416);       // 64x768x128       12,582,912
  f16*   scbuf = (f16*)(ws + 132835328);       // 4096x768          6,291,456
  // total ws used: 139,126,784 B

  prep<<<4096, 256, 0, stream>>>(Wmo, hj, y, emb, Wa, Wih, Whhf, bmo,
                                 Wpair, Ahj, Ae, Wah, Wasp, Whhp, Wct, Wet, biasp);
  // hj_proj = h_j @ W_a_h^T   (8192x512 x 512->256)
  gemm_k<0><<<128, 256, 0, stream>>>(Ahj, Wah, hjp, nullptr, 512, 256, 64);
  // gi_e = emb_eff[y] @ W_e^T + b_ih   (4096x128 x 128->768)
  gemm_k<1><<<192, 256, 0, stream>>>(Ae, Wet, gie, bih, 128, 768, 32);
  // hjWc = h_j @ W_c^T  stored transposed per batch  (8192x512 x 512->768)
  gemm_k<2><<<384, 256, 0, stream>>>(Ahj, Wct, hjWcT, nullptr, 512, 768, 64);
  // sequential GRU + attention, 1 block per batch
  recur_k<<<64, 512, 0, stream>>>(Whhp, Wasp, hjWcT, hjp, Ahj, gie, bhh, va, scbuf);
  // out = pairmax([s,c] @ W_pair^T + bias_pair)   (4096x768 x 768->64000)
  gemm_k<3><<<16000, 256, 0, stream>>>(scbuf, Wpair, d_out, biasp, 768, 64000, 32);
}

// Round 2
// 3343.104 us; speedup vs baseline: 3.8876x; 3.8876x over previous
//
#include <hip/hip_runtime.h>
#include <hip/hip_fp16.h>
#include <stdint.h>

typedef _Float16 f16;
typedef _Float16 v2h __attribute__((ext_vector_type(2)));
typedef _Float16 v8h __attribute__((ext_vector_type(8)));
typedef float v4f __attribute__((ext_vector_type(4)));

#define AS1 __attribute__((address_space(1)))
#define AS3 __attribute__((address_space(3)))

__device__ __forceinline__ void gld_lds16(const f16* g, f16* l) {
  __builtin_amdgcn_global_load_lds((AS1 void*)g, (AS3 void*)l, 16, 0, 0);
}

__device__ __forceinline__ float fsig(float x) { return 1.f / (1.f + __expf(-x)); }
__device__ __forceinline__ float ftanh(float x) {
  float e = __expf(2.f * x);
  return 1.f - 2.f / (e + 1.f);
}

// dot of 8 f16 pairs via v_dot2_f32_f16
__device__ __forceinline__ float dot8d(v8h w, v8h s, float acc) {
  acc = __builtin_amdgcn_fdot2(__builtin_shufflevector(w, w, 0, 1),
                               __builtin_shufflevector(s, s, 0, 1), acc, false);
  acc = __builtin_amdgcn_fdot2(__builtin_shufflevector(w, w, 2, 3),
                               __builtin_shufflevector(s, s, 2, 3), acc, false);
  acc = __builtin_amdgcn_fdot2(__builtin_shufflevector(w, w, 4, 5),
                               __builtin_shufflevector(s, s, 4, 5), acc, false);
  acc = __builtin_amdgcn_fdot2(__builtin_shufflevector(w, w, 6, 7),
                               __builtin_shufflevector(s, s, 6, 7), acc, false);
  return acc;
}

__device__ __forceinline__ void st4h(f16* d, float4 f) {
  union { f16 h[4]; uint2 u; } o;
  o.h[0] = (f16)f.x; o.h[1] = (f16)f.y; o.h[2] = (f16)f.z; o.h[3] = (f16)f.w;
  *(uint2*)d = o.u;
}

// ---------------- prep: fp32->fp16 conversions / gathers / reorders ----------
// W_pair row r: j=(r>>4)&1, v=(r>>5)*16+(r&15)  (pair partners 16 rows apart,
// so the final-GEMM epilogue max is in-lane between ni and ni+1 tiles)
#define C_WPAIR 12288000ULL
#define C_AHJ   (C_WPAIR + 1048576ULL)
#define C_AE    (C_AHJ + 131072ULL)
#define C_WAH   (C_AE + 32768ULL)
#define C_WAS   (C_WAH + 16384ULL)
#define C_WHH   (C_WAS + 49152ULL)
#define C_WCT   (C_WHH + 98304ULL)
#define C_WET   (C_WCT + 24576ULL)
#define C_BIASP (C_WET + 16000ULL)

__global__ __launch_bounds__(256) void prep(
    const float* __restrict__ Wmo, const float* __restrict__ hj,
    const int* __restrict__ y, const float* __restrict__ emb,
    const float* __restrict__ Wa, const float* __restrict__ Wih,
    const float* __restrict__ Whhf, const float* __restrict__ bmo,
    f16* __restrict__ Wpair, f16* __restrict__ Ahj, f16* __restrict__ Ae,
    f16* __restrict__ Wah, f16* __restrict__ Was, f16* __restrict__ Whh,
    f16* __restrict__ Wct, f16* __restrict__ Wet, float* __restrict__ biasp)
{
  for (size_t g = (size_t)blockIdx.x * blockDim.x + threadIdx.x; g < C_BIASP;
       g += (size_t)gridDim.x * blockDim.x) {
    if (g < C_WPAIR) {
      size_t row = g / 192, kk = (g % 192) * 4;
      size_t jj = (row >> 4) & 1, v = (row >> 5) * 16 + (row & 15);
      float4 f = *(const float4*)(Wmo + (jj * 32000 + v) * 768 + kk);
      st4h(Wpair + row * 768 + kk, f);
    } else if (g < C_AHJ) {                  // h_j flat -> f16 (8192x512)
      size_t i = (g - C_WPAIR) * 4;
      float4 f = *(const float4*)(hj + i);
      st4h(Ahj + i, f);
    } else if (g < C_AE) {                   // emb gather, rows m = t*64+b
      size_t i = g - C_AHJ;
      size_t m = i >> 5, kk = (i & 31) * 4;
      int yy = y[(m & 63) * 64 + (m >> 6)];
      float4 f = make_float4(0.f, 0.f, 0.f, 0.f);
      if (yy != 0) f = *(const float4*)(emb + (size_t)yy * 128 + kk);
      st4h(Ae + m * 128 + kk, f);
    } else if (g < C_WAH) {                  // W_a[:,256:768] rows (256x512)
      size_t i = g - C_AE;
      size_t n = i >> 7, kk = (i & 127) * 4;
      float4 f = *(const float4*)(Wa + n * 768 + 256 + kk);
      st4h(Wah + n * 512 + kk, f);
    } else if (g < C_WAS) {                  // W_a[:,0:256] rows (256x256)
      size_t i = g - C_WAH;
      size_t n = i >> 6, kk = (i & 63) * 4;
      float4 f = *(const float4*)(Wa + n * 768 + kk);
      st4h(Was + n * 256 + kk, f);
    } else if (g < C_WHH) {                  // W_hh copy (768x256)
      size_t i = (g - C_WAS) * 4;
      float4 f = *(const float4*)(Whhf + i);
      st4h(Whh + i, f);
    } else if (g < C_WCT) {                  // W_ih[:,128:640] rows (768x512)
      size_t i = g - C_WHH;
      size_t n = i >> 7, kk = (i & 127) * 4;
      float4 f = *(const float4*)(Wih + n * 640 + 128 + kk);
      st4h(Wct + n * 512 + kk, f);
    } else if (g < C_WET) {                  // W_ih[:,0:128] rows (768x128)
      size_t i = g - C_WCT;
      size_t n = i >> 5, kk = (i & 31) * 4;
      float4 f = *(const float4*)(Wih + n * 640 + kk);
      st4h(Wet + n * 128 + kk, f);
    } else {                                 // bias_pair, same mapping as Wpair
      size_t i = g - C_WET;
      size_t n = i * 4;
#pragma unroll
      for (int u = 0; u < 4; ++u) {
        size_t nn = n + u;
        size_t jj = (nn >> 4) & 1, v = (nn >> 5) * 16 + (nn & 15);
        biasp[nn] = bmo[jj * 32000 + v];
      }
    }
  }
}

// ---------------- generic 128x128x(BK=32) fp16 MFMA GEMM, C = A * Bt^T -------
// LDS chunk index XOR-swizzled by (row>>1)&3 to break the 64B-stride bank alias.
// MODE 0: f16 C[m*N+n]; MODE 1: + bias; MODE 2: f16 C[((m>>7)*N+n)*128+(m&127)]
// MODE 3: pair-max epilogue (pairs 16 apart in n -> in-lane max), f32 out.
template <int MODE>
__global__ __launch_bounds__(256) void gemm_k(
    const f16* __restrict__ A, const f16* __restrict__ Bt,
    void* __restrict__ Cout, const float* __restrict__ bias,
    int K, int N, int gridMtiles)
{
  __shared__ __align__(16) f16 As[128 * 32];
  __shared__ __align__(16) f16 Bs[128 * 32];
  const int bid = blockIdx.x;
  const int mt = bid % gridMtiles, nt = bid / gridMtiles;
  const int m0 = mt << 7, n0 = nt << 7;
  const int tid = threadIdx.x;
  const int wave = tid >> 6, lane = tid & 63;
  const int sr = lane >> 2;                       // staging row-in-16
  const int schunk = (lane & 3) ^ ((sr >> 1) & 3);// swizzled source chunk
  const int q = lane >> 4, rm = lane & 15;
  const int rswz = (rm >> 1) & 3;
  const int wm = (wave & 1) << 6, wn = (wave >> 1) << 6;

  v4f acc[4][4];
#pragma unroll
  for (int i = 0; i < 4; ++i)
#pragma unroll
    for (int j = 0; j < 4; ++j) acc[i][j] = (v4f){0.f, 0.f, 0.f, 0.f};

  const f16* Abase = A + (size_t)m0 * K;
  const f16* Bbase = Bt + (size_t)n0 * K;

  for (int k0 = 0; k0 < K; k0 += 32) {
#pragma unroll
    for (int p = 0; p < 2; ++p) {
      const int c = wave * 2 + p;
      const int r = c * 16 + sr;
      gld_lds16(Abase + (size_t)r * K + k0 + schunk * 8, As + c * 512);
      gld_lds16(Bbase + (size_t)r * K + k0 + schunk * 8, Bs + c * 512);
    }
    __syncthreads();
    v8h af[4], bf[4];
#pragma unroll
    for (int i = 0; i < 4; ++i) {
      af[i] = *(const v8h*)(As + (wm + i * 16 + rm) * 32 + ((q ^ rswz) * 8));
      bf[i] = *(const v8h*)(Bs + (wn + i * 16 + rm) * 32 + ((q ^ rswz) * 8));
    }
#pragma unroll
    for (int mi = 0; mi < 4; ++mi)
#pragma unroll
      for (int ni = 0; ni < 4; ++ni)
        acc[mi][ni] = __builtin_amdgcn_mfma_f32_16x16x32_f16(
            af[mi], bf[ni], acc[mi][ni], 0, 0, 0);
    __syncthreads();
  }

#pragma unroll
  for (int mi = 0; mi < 4; ++mi) {
    if constexpr (MODE == 3) {
#pragma unroll
      for (int ni2 = 0; ni2 < 2; ++ni2)
#pragma unroll
        for (int reg = 0; reg < 4; ++reg) {
          const int gm = m0 + wm + mi * 16 + q * 4 + reg;
          const int gn = n0 + wn + ni2 * 32 + rm;    // even-ni tile column
          float v0 = acc[mi][ni2 * 2][reg] + bias[gn];
          float v1 = acc[mi][ni2 * 2 + 1][reg] + bias[gn + 16];
          ((float*)Cout)[(size_t)gm * 32000 + (size_t)(gn >> 5) * 16 + rm] =
              fmaxf(v0, v1);
        }
    } else {
#pragma unroll
      for (int ni = 0; ni < 4; ++ni)
#pragma unroll
        for (int reg = 0; reg < 4; ++reg) {
          const int gm = m0 + wm + mi * 16 + q * 4 + reg;
          const int gn = n0 + wn + ni * 16 + rm;
          float v = acc[mi][ni][reg];
          if constexpr (MODE == 0) {
            ((f16*)Cout)[(size_t)gm * N + gn] = (f16)v;
          } else if constexpr (MODE == 1) {
            v += bias[gn];
            ((f16*)Cout)[(size_t)gm * N + gn] = (f16)v;
          } else {
            ((f16*)Cout)[((size_t)(gm >> 7) * N + gn) * 128 + (gm & 127)] = (f16)v;
          }
        }
    }
  }
}

// ---------------- recurrence: 1 block per batch, 64 steps ---------------------
// c_new moved OUT of the loop (alphas stored, cgemm computes c after).
// hjp slice + Whh n-gate rows live in registers across all steps.
__global__ __launch_bounds__(512) void recur_k(
    const f16* __restrict__ Whh, const f16* __restrict__ Was,
    const f16* __restrict__ hjWcT, const f16* __restrict__ hjp,
    const f16* __restrict__ gie, const float* __restrict__ bhh,
    const float* __restrict__ va, f16* __restrict__ sc,
    f16* __restrict__ alphasT)
{
  const int b = blockIdx.x, tid = threadIdx.x;
  const int wv = tid >> 6, lane = tid & 63;
  const int ks = lane >> 4, hl = lane & 15;
  __shared__ __align__(16) f16 s_buf[2][256];
  __shared__ __align__(16) f16 alpha[128];
  __shared__ __align__(16) f16 sp[256];
  __shared__ __align__(16) f16 va_l[256];
  __shared__ float energy[128];
  __shared__ float bhh_l[768];

  for (int i = tid; i < 768; i += 512) bhh_l[i] = bhh[i];
  if (tid < 256) { va_l[tid] = (f16)va[tid]; s_buf[0][tid] = (f16)0.f; }
  if (tid < 128) alpha[tid] = (f16)0.f;

  const f16* hjWb = hjWcT + (size_t)b * 98304;  // 768*128
  const f16* hjpb = hjp + (size_t)b * 32768;    // 128*256

  // register-resident: Whh n-gate rows (2 h per thread, 64B k-slice each)
  v8h whn[2][8];
#pragma unroll
  for (int hg = 0; hg < 2; ++hg) {
    const int h = wv * 32 + hg * 16 + hl;
#pragma unroll
    for (int i = 0; i < 8; ++i)
      whn[hg][i] = *(const v8h*)(Whh + (size_t)(512 + h) * 256 + ks * 64 + i * 8);
  }
  // register-resident: hjp row slice for phase C
  const int tx = wv * 16 + hl;
  v8h hjr[8];
#pragma unroll
  for (int i = 0; i < 8; ++i)
    hjr[i] = *(const v8h*)(hjpb + (size_t)tx * 256 + ks * 64 + i * 8);
  __syncthreads();

  for (int t = 0; t < 64; ++t) {
    const int cur = t & 1, nxt = cur ^ 1;
    const size_t srow = ((size_t)b * 64 + t) * 768;
    const f16* grow = gie + ((size_t)t * 64 + b) * 768;

    v8h sA[8], aA[4];
#pragma unroll
    for (int i = 0; i < 8; ++i) sA[i] = *(const v8h*)(&s_buf[cur][ks * 64 + i * 8]);
#pragma unroll
    for (int i = 0; i < 4; ++i) aA[i] = *(const v8h*)(&alpha[ks * 32 + i * 8]);

    // ---- phase A: gates -> s_new
#pragma unroll
    for (int hg = 0; hg < 2; ++hg) {
      const int h = wv * 32 + hg * 16 + hl;
      float d_r = 0.f, d_z = 0.f, g_n = 0.f, e_n = 0.f;
      const f16* wr = Whh + (size_t)h * 256 + ks * 64;
      const f16* wz = Whh + (size_t)(256 + h) * 256 + ks * 64;
      const f16* cr = hjWb + (size_t)h * 128 + ks * 32;
      const f16* cz = hjWb + (size_t)(256 + h) * 128 + ks * 32;
      const f16* cn = hjWb + (size_t)(512 + h) * 128 + ks * 32;
#pragma unroll
      for (int i = 0; i < 8; ++i) {
        d_r = dot8d(*(const v8h*)(wr + i * 8), sA[i], d_r);
        d_z = dot8d(*(const v8h*)(wz + i * 8), sA[i], d_z);
        g_n = dot8d(whn[hg][i], sA[i], g_n);
      }
#pragma unroll
      for (int i = 0; i < 4; ++i) {
        d_r = dot8d(*(const v8h*)(cr + i * 8), aA[i], d_r);
        d_z = dot8d(*(const v8h*)(cz + i * 8), aA[i], d_z);
        e_n = dot8d(*(const v8h*)(cn + i * 8), aA[i], e_n);
      }
      d_r += __shfl_xor(d_r, 16); d_r += __shfl_xor(d_r, 32);
      d_z += __shfl_xor(d_z, 16); d_z += __shfl_xor(d_z, 32);
      g_n += __shfl_xor(g_n, 16); g_n += __shfl_xor(g_n, 32);
      e_n += __shfl_xor(e_n, 16); e_n += __shfl_xor(e_n, 32);
      if (ks == 0) {
        float rr = fsig(bhh_l[h] + (float)grow[h] + d_r);
        float zz = fsig(bhh_l[256 + h] + (float)grow[256 + h] + d_z);
        float nn = ftanh((float)grow[512 + h] + e_n + rr * (bhh_l[512 + h] + g_n));
        float sn = (1.f - zz) * nn + zz * (float)s_buf[cur][h];
        s_buf[nxt][h] = (f16)sn;
        sc[srow + h] = (f16)sn;
      }
    }
    __syncthreads();

    // ---- phase B: s_proj = s_new . W_a_s rows
    {
      v8h sN[8];
#pragma unroll
      for (int i = 0; i < 8; ++i) sN[i] = *(const v8h*)(&s_buf[nxt][ks * 64 + i * 8]);
#pragma unroll
      for (int hg = 0; hg < 2; ++hg) {
        const int h = wv * 32 + hg * 16 + hl;
        const f16* wa = Was + (size_t)h * 256 + ks * 64;
        float a2 = 0.f;
#pragma unroll
        for (int i = 0; i < 8; ++i) a2 = dot8d(*(const v8h*)(wa + i * 8), sN[i], a2);
        a2 += __shfl_xor(a2, 16); a2 += __shfl_xor(a2, 32);
        if (ks == 0) sp[h] = (f16)a2;
      }
    }
    __syncthreads();

    // ---- phase C: energy[tx] = sum_h tanh(sp+hjp)*va   (hjp in regs)
    {
      float a3 = 0.f;
#pragma unroll
      for (int i = 0; i < 8; ++i) {
        v8h hj8 = hjr[i];
        v8h sp8 = *(const v8h*)(&sp[ks * 64 + i * 8]);
        v8h va8 = *(const v8h*)(&va_l[ks * 64 + i * 8]);
#pragma unroll
        for (int j = 0; j < 8; ++j)
          a3 += ftanh((float)sp8[j] + (float)hj8[j]) * (float)va8[j];
      }
      a3 += __shfl_xor(a3, 16); a3 += __shfl_xor(a3, 32);
      if (ks == 0) energy[tx] = a3;
    }
    __syncthreads();

    // ---- softmax over tx (one wave), store alphas (transposed) for cgemm
    if (tid < 64) {
      float e0 = energy[tid], e1 = energy[tid + 64];
      float mx = fmaxf(e0, e1);
#pragma unroll
      for (int off = 32; off; off >>= 1) mx = fmaxf(mx, __shfl_xor(mx, off));
      float x0 = __expf(e0 - mx), x1 = __expf(e1 - mx);
      float ssum = x0 + x1;
#pragma unroll
      for (int off = 32; off; off >>= 1) ssum += __shfl_xor(ssum, off);
      float inv = 1.f / ssum;
      float a0 = x0 * inv, a1 = x1 * inv;
      alpha[tid] = (f16)a0;
      alpha[tid + 64] = (f16)a1;
      alphasT[((size_t)b * 128 + tid) * 64 + t] = (f16)a0;
      alphasT[((size_t)b * 128 + tid + 64) * 64 + t] = (f16)a1;
    }
    __syncthreads();
  }
}

// ---------------- c = alpha @ h_j, batched, parallel (moved out of recur) ----
__global__ __launch_bounds__(512) void cgemm(
    const f16* __restrict__ hjf, const f16* __restrict__ alphasT,
    f16* __restrict__ sc)
{
  const int b = blockIdx.x, k = threadIdx.x;
  float acc[64];
#pragma unroll
  for (int t = 0; t < 64; ++t) acc[t] = 0.f;
  const f16* hp = hjf + (size_t)b * 65536 + k;
  const f16* ap = alphasT + (size_t)b * 8192;
  for (int txb = 0; txb < 128; ++txb) {
    float h = (float)hp[(size_t)txb * 512];
    const f16* a = ap + txb * 64;
#pragma unroll
    for (int tb = 0; tb < 8; ++tb) {
      v8h a8 = *(const v8h*)(a + tb * 8);
#pragma unroll
      for (int j = 0; j < 8; ++j) acc[tb * 8 + j] += (float)a8[j] * h;
    }
  }
#pragma unroll
  for (int t = 0; t < 64; ++t)
    sc[((size_t)b * 64 + t) * 768 + 256 + k] = (f16)acc[t];
}

// ---------------- launch ------------------------------------------------------
extern "C" void kernel_launch(void* const* d_in, const int* in_sizes, int n_in,
                              void* d_out, int out_size, void* d_ws, size_t ws_size,
                              hipStream_t stream)
{
  const int*   y    = (const int*)d_in[0];
  const float* hj   = (const float*)d_in[1];
  const float* emb  = (const float*)d_in[2];
  const float* Wih  = (const float*)d_in[3];
  const float* Whhf = (const float*)d_in[4];
  const float* bih  = (const float*)d_in[5];
  const float* bhh  = (const float*)d_in[6];
  const float* Wa   = (const float*)d_in[7];
  const float* va   = (const float*)d_in[8];
  const float* Wmo  = (const float*)d_in[9];
  const float* bmo  = (const float*)d_in[10];

  char* ws = (char*)d_ws;
  f16*   Wpair = (f16*)(ws);                   // 64000x768        98,304,000 B
  f16*   Ahj   = (f16*)(ws + 98304000);        // 8192x512          8,388,608
  f16*   Ae    = (f16*)(ws + 106692608);       // 4096x128          1,048,576
  f16*   Wah   = (f16*)(ws + 107741184);       // 256x512             262,144
  f16*   Wasp  = (f16*)(ws + 108003328);       // 256x256             131,072
  f16*   Whhp  = (f16*)(ws + 108134400);       // 768x256             393,216
  f16*   Wct   = (f16*)(ws + 108527616);       // 768x512             786,432
  f16*   Wet   = (f16*)(ws + 109314048);       // 768x128             196,608
  float* biasp = (float*)(ws + 109510656);     // 64000               256,000
  f16*   hjp   = (f16*)(ws + 109766656);       // 8192x256          4,194,304
  f16*   gie   = (f16*)(ws + 113960960);       // 4096x768          6,291,456
  f16*   hjWcT = (f16*)(ws + 120252416);       // 64x768x128       12,582,912
  f16*   scbuf = (f16*)(ws + 132835328);       // 4096x768          6,291,456
  // alphasT (64x128x64 f16 = 1,048,576 B) reuses the Ae region: Ae is fully
  // consumed by gemm_k<1> before recur_k writes alphasT (stream-ordered).
  f16*   alphasT = Ae;

  prep<<<4096, 256, 0, stream>>>(Wmo, hj, y, emb, Wa, Wih, Whhf, bmo,
                                 Wpair, Ahj, Ae, Wah, Wasp, Whhp, Wct, Wet, biasp);
  // hj_proj = h_j @ W_a_h^T   (8192x512 x 512->256)
  gemm_k<0><<<128, 256, 0, stream>>>(Ahj, Wah, hjp, nullptr, 512, 256, 64);
  // gi_e = emb_eff[y] @ W_e^T + b_ih   (4096x128 x 128->768)
  gemm_k<1><<<192, 256, 0, stream>>>(Ae, Wet, gie, bih, 128, 768, 32);
  // hjWc = h_j @ W_c^T  stored transposed per batch  (8192x512 x 512->768)
  gemm_k<2><<<384, 256, 0, stream>>>(Ahj, Wct, hjWcT, nullptr, 512, 768, 64);
  // sequential GRU + attention, 1 block per batch (c_new deferred)
  recur_k<<<64, 512, 0, stream>>>(Whhp, Wasp, hjWcT, hjp, gie, bhh, va,
                                  scbuf, alphasT);
  // c = alpha @ h_j  (parallel, fills sc columns 256..768)
  cgemm<<<64, 512, 0, stream>>>(Ahj, alphasT, scbuf);
  // out = pairmax([s,c] @ W_pair^T + bias_pair)   (4096x768 x 768->64000)
  gemm_k<3><<<16000, 256, 0, stream>>>(scbuf, Wpair, d_out, biasp, 768, 64000, 32);
}